// Round 5
// baseline (10137.746 us; speedup 1.0000x reference)
//
#include <hip/hip_runtime.h>
#include <hip/hip_bf16.h>

#define Bn   1024
#define Tn   730
#define INn  64
#define Hn   512
#define Kn   576      // INn + Hn
#define G4n  2048     // 4*Hn

typedef __bf16 bf16x8 __attribute__((ext_vector_type(8)));
typedef float  f32x4  __attribute__((ext_vector_type(4)));

// LDS: A-tile 32x576 bf16 (fragment order) = 36864 B, then kh-exchange region:
// 4 wq x 2 rg x 4 gates x 64 lanes x 16B = 32768 B. All accesses lane-contiguous b128.
#define XCH_OFF 36864

// ---------------- weight pre-pack: Wc[row][k] bf16, row = gate*512+j, k over [x|h] ----------
__global__ void convert_weights(const float* __restrict__ Wih,
                                const float* __restrict__ Whh,
                                __bf16* __restrict__ Wc) {
    int idx = blockIdx.x * 256 + threadIdx.x;
    if (idx >= G4n * Kn) return;
    int row = idx / Kn;
    int k   = idx - row * Kn;
    float v = (k < INn) ? Wih[row * INn + k] : Whh[row * Hn + (k - INn)];
    Wc[idx] = (__bf16)v;
}

// fast sigmoid: v_exp + single v_rcp (error ~1ulp << bf16 h-quantization)
__device__ __forceinline__ float sigf(float x)   { return __builtin_amdgcn_rcpf(1.0f + __expf(-x)); }
__device__ __forceinline__ float tanhf_f(float x){ return 2.0f * sigf(2.0f * x) - 1.0f; }

// ---------------- persistent LSTM scan ----------------
// 256 blocks x 512 threads (8 waves), 1 block/CU. Block = (rg_i: 32 batch rows) x (cb: 64 h-cols).
// Wave role: kh = wave&1 (K-half 288), wq = wave>>1 (16 h-cols). Each wave holds ALL 4
// GATES for its 16 cols (wreg[kb][gate], 144 regs) -> after the kh partial-sum exchange,
// i/f/g/o for a cell are IN-LANE: no z matrix in LDS at all. The exchange moves raw MFMA
// fragments (identical layout in kh partners): wave finalizes row-group rg==kh, writes the
// other rg's 4 frags (4 ds_write_b128), reads partner's (4 ds_read_b128), sums, gates,
// stores h as 4x2B agent-scope stores (rows are register-separated; WRITE inflation
// accepted, HBM write BW has 30x headroom).
// COHERENCE (proven scheme): all cross-block data via RELAXED agent-scope atomics
// (write-through/bypass to IC); __syncthreads drains vmcnt(0) before the barrier bump.
__global__ __launch_bounds__(512, 1) void lstm_persist(
    const float* __restrict__ xd,     // [B,T,IN]
    const float* __restrict__ bias,   // [4H]
    const __bf16* __restrict__ Wc,    // [4H][Kn]
    __bf16* __restrict__ h0,          // [B,H] buffer A (final h lands here)
    __bf16* __restrict__ h1,          // [B,H] buffer B
    unsigned int* __restrict__ bar)   // 32 groups x 32 uints (128B stride)
{
    __shared__ __align__(16) char smem[XCH_OFF + 32768];
    bf16x8* aTile = (bf16x8*)smem;
    f32x4*  xch   = (f32x4*)(smem + XCH_OFF);

    const int blk  = blockIdx.x;
    // group (rg_i) pinned to one XCD-slot (blk&7); 8 col-blocks per group
    const int rg_i = (blk & 7) * 4 + ((blk >> 3) & 3);   // 0..31 row-group
    const int cb   = blk >> 5;                           // 0..7  col-block
    const int m0   = rg_i << 5;
    const int j0   = cb << 6;

    const int tid  = threadIdx.x;              // 0..511
    const int wave = tid >> 6;                 // 0..7
    const int lane = tid & 63;
    const int q    = lane >> 4;
    const int l16  = lane & 15;

    const int kh   = wave & 1;                 // K half: kb 9*kh .. 9*kh+8
    const int wq   = wave >> 1;                // 16-col group (all 4 gates)
    const int myrg = kh;                       // row-group this wave finalizes
    const int org  = 1 - kh;                   // row-group it exports

    // ---- resident weights: 9 kb x 4 gates for cols j0 + wq*16 + l16 (144 regs) ----
    bf16x8 wreg[9][4];
    float  bini[4];
    const int wcol = j0 + wq * 16 + l16;
    #pragma unroll
    for (int cg = 0; cg < 4; ++cg) {
        #pragma unroll
        for (int kb = 0; kb < 9; ++kb)
            wreg[kb][cg] = *(const bf16x8*)(Wc + (size_t)(cg * Hn + wcol) * Kn
                                               + (kh * 9 + kb) * 32 + q * 8);
        bini[cg] = bias[cg * Hn + wcol];       // folded into acc[myrg] init (added once)
    }

    // ---- c-state: 4 cells/lane (rows m0 + myrg*16 + q*4 + e, col wcol) ----
    float creg[4] = {0.f, 0.f, 0.f, 0.f};

    // ---- x staging: kh==0 waves, frag (xrg = wq>>1, xkb = wq&1) ----
    const bool  xown = (kh == 0);
    const float* xrb = xd + (size_t)(m0 + (wq >> 1) * 16 + l16) * (Tn * INn)
                          + (wq & 1) * 32 + q * 8;
    const int   xslot = ((wq >> 1) * 18 + (wq & 1)) * 64 + lane;

    unsigned int* cnt = bar + (rg_i << 5);     // one 128B line per group
    bool dead = false;

    // ---- prologue: stage x(t=0) ----
    if (xown) {
        f32x4 lo = *(const f32x4*)xrb;
        f32x4 hi = *(const f32x4*)(xrb + 4);
        bf16x8 v;
        v[0] = (__bf16)lo[0]; v[1] = (__bf16)lo[1]; v[2] = (__bf16)lo[2]; v[3] = (__bf16)lo[3];
        v[4] = (__bf16)hi[0]; v[5] = (__bf16)hi[1]; v[6] = (__bf16)hi[2]; v[7] = (__bf16)hi[3];
        aTile[xslot] = v;
    }

    for (int t = 0; t < Tn; ++t) {
        const __bf16* hread  = (t & 1) ? h1 : h0;
        __bf16*       hwrite = (t & 1) ? h0 : h1;

        // ---- phase 1: h -> regs (8 u64 loads all in flight), then -> LDS ----
        unsigned long long hu[4][2];
        #pragma unroll
        for (int i = 0; i < 4; ++i) {
            const int hf  = wave * 4 + i;
            const int rg  = hf >> 4;
            const int kbh = hf & 15;
            const unsigned long long* hp = (const unsigned long long*)
                (hread + (size_t)(m0 + rg * 16 + l16) * Hn + kbh * 32 + q * 8);
            hu[i][0] = __hip_atomic_load(hp,     __ATOMIC_RELAXED, __HIP_MEMORY_SCOPE_AGENT);
            hu[i][1] = __hip_atomic_load(hp + 1, __ATOMIC_RELAXED, __HIP_MEMORY_SCOPE_AGENT);
        }
        #pragma unroll
        for (int i = 0; i < 4; ++i) {
            const int hf  = wave * 4 + i;
            const int rg  = hf >> 4;
            const int kbh = hf & 15;
            union { unsigned long long u[2]; bf16x8 v; } cv;
            cv.u[0] = hu[i][0]; cv.u[1] = hu[i][1];
            aTile[(rg * 18 + kbh + 2) * 64 + lane] = cv.v;
        }
        __syncthreads();

        // ---- phase 2: MFMA (2 rg x 4 gates x 9 kb); bias into acc[myrg] init ----
        f32x4 acc[2][4];
        #pragma unroll
        for (int rg = 0; rg < 2; ++rg)
            #pragma unroll
            for (int cg = 0; cg < 4; ++cg) {
                const float bv = (rg == myrg) ? bini[cg] : 0.f;
                acc[rg][cg] = (f32x4){bv, bv, bv, bv};
            }
        #pragma unroll
        for (int kb = 0; kb < 9; ++kb) {
            const bf16x8 af0 = aTile[(0 * 18 + kh * 9 + kb) * 64 + lane];
            const bf16x8 af1 = aTile[(1 * 18 + kh * 9 + kb) * 64 + lane];
            #pragma unroll
            for (int cg = 0; cg < 4; ++cg) {
                acc[0][cg] = __builtin_amdgcn_mfma_f32_16x16x32_bf16(af0, wreg[kb][cg], acc[0][cg], 0, 0, 0);
                acc[1][cg] = __builtin_amdgcn_mfma_f32_16x16x32_bf16(af1, wreg[kb][cg], acc[1][cg], 0, 0, 0);
            }
        }
        // export the row-group the kh-partner finalizes (4 b128, lane-contiguous)
        #pragma unroll
        for (int cg = 0; cg < 4; ++cg)
            xch[((wq * 2 + org) * 4 + cg) * 64 + lane] = acc[org][cg];
        __syncthreads();

        // ---- phase 3: partner sum + in-lane gates; x(t+1) under the latency ----
        f32x4 xlo, xhi;
        const bool mx = xown && (t + 1 < Tn);
        if (mx) {
            const float* xp = xrb + (size_t)(t + 1) * INn;
            xlo = *(const f32x4*)xp;
            xhi = *(const f32x4*)(xp + 4);
        }
        float zs[4][4];
        #pragma unroll
        for (int cg = 0; cg < 4; ++cg) {
            const f32x4 p = xch[((wq * 2 + myrg) * 4 + cg) * 64 + lane];
            #pragma unroll
            for (int e = 0; e < 4; ++e) zs[cg][e] = acc[myrg][cg][e] + p[e];
        }
        __bf16* hcb = hwrite + (size_t)(m0 + myrg * 16 + q * 4) * Hn + wcol;
        #pragma unroll
        for (int e = 0; e < 4; ++e) {
            const float cn = sigf(zs[1][e]) * creg[e]
                           + sigf(zs[0][e]) * tanhf_f(zs[2][e]);
            creg[e] = cn;
            union { __bf16 b; unsigned short u; } hv;
            hv.b = (__bf16)(sigf(zs[3][e]) * tanhf_f(cn));
            __hip_atomic_store((unsigned short*)(hcb + (size_t)e * Hn),
                               hv.u, __ATOMIC_RELAXED, __HIP_MEMORY_SCOPE_AGENT);
        }

        // finish x(t+1) staging (loads have had the gate math to land)
        if (mx) {
            bf16x8 v;
            v[0] = (__bf16)xlo[0]; v[1] = (__bf16)xlo[1]; v[2] = (__bf16)xlo[2]; v[3] = (__bf16)xlo[3];
            v[4] = (__bf16)xhi[0]; v[5] = (__bf16)xhi[1]; v[6] = (__bf16)xhi[2]; v[7] = (__bf16)xhi[3];
            aTile[xslot] = v;
        }

        // ---- phase 4: group barrier (8 blocks sharing rg_i), relaxed atomics only ----
        __syncthreads();   // drains vmcnt(0): all write-through h stores at IC
        if (tid == 0) {
            __hip_atomic_fetch_add(cnt, 1u, __ATOMIC_RELAXED, __HIP_MEMORY_SCOPE_AGENT);
            if (!dead) {
                const unsigned int target = 8u * (unsigned int)(t + 1);
                int spins = 0;
                while (__hip_atomic_load(cnt, __ATOMIC_RELAXED, __HIP_MEMORY_SCOPE_AGENT) < target) {
                    __builtin_amdgcn_s_sleep(2);
                    if (++spins > 300000) { dead = true; break; }  // hang -> fast wrong-answer
                }
            }
        }
        __syncthreads();
    }
}

// ---------------- head: out[b] = relu(dot(h_T[b], Wl) + bl) ----------------
__global__ void head_kernel(const __bf16* __restrict__ h, const float* __restrict__ Wl,
                            const float* __restrict__ bl, float* __restrict__ out) {
    const int b = blockIdx.x;
    const int lane = threadIdx.x;  // 64 threads
    const __bf16* hp = h + (size_t)b * Hn;
    float s = 0.f;
    #pragma unroll
    for (int j = lane; j < Hn; j += 64) s += (float)hp[j] * Wl[j];
    #pragma unroll
    for (int off = 32; off > 0; off >>= 1) s += __shfl_down(s, off, 64);
    if (lane == 0) out[b] = fmaxf(s + bl[0], 0.0f);
}

extern "C" void kernel_launch(void* const* d_in, const int* in_sizes, int n_in,
                              void* d_out, int out_size, void* d_ws, size_t ws_size,
                              hipStream_t stream) {
    const float* xd  = (const float*)d_in[0];
    const float* Wih = (const float*)d_in[1];
    const float* Whh = (const float*)d_in[2];
    const float* b   = (const float*)d_in[3];
    const float* Wl  = (const float*)d_in[4];
    const float* bl  = (const float*)d_in[5];
    float* out = (float*)d_out;

    // ws layout:
    //   Wc  bf16 [2048][576] : 2,359,296 B
    //   h0  bf16 [1024][512] : 1,048,576 B
    //   h1  bf16 [1024][512] : 1,048,576 B
    //   bar u32  [32][32]    : 4,096 B
    char* ws = (char*)d_ws;
    __bf16* Wc = (__bf16*)ws;
    __bf16* h0 = (__bf16*)(ws + 2359296);
    __bf16* h1 = (__bf16*)(ws + 2359296 + 1048576);
    unsigned int* bar = (unsigned int*)(ws + 2359296 + 2 * 1048576);

    hipMemsetAsync(h0, 0, 1048576, stream);   // t=0 reads h0 as zeros
    hipMemsetAsync(bar, 0, 4096, stream);     // monotonic barrier counters (32 groups)

    const int total = G4n * Kn;
    convert_weights<<<(total + 255) / 256, 256, 0, stream>>>(Wih, Whh, Wc);

    lstm_persist<<<256, 512, 0, stream>>>(xd, b, Wc, h0, h1, bar);

    // t=729 (odd) writes h0 -> final hidden state is in h0
    head_kernel<<<Bn, 64, 0, stream>>>(h0, Wl, bl, out);
}

// Round 6
// 4433.504 us; speedup vs baseline: 2.2866x; 2.2866x over previous
//
#include <hip/hip_runtime.h>
#include <hip/hip_bf16.h>

#define Bn   1024
#define Tn   730
#define INn  64
#define Hn   512
#define Kn   576      // INn + Hn
#define G4n  2048     // 4*Hn

typedef __bf16 bf16x8 __attribute__((ext_vector_type(8)));
typedef float  f32x4  __attribute__((ext_vector_type(4)));

// LDS: A-tile 32x576 bf16 (fragment order) = 36864 B, then kh-exchange region:
// 4 wq x 2 rg x 4 gates x 64 lanes x 16B = 32768 B. All accesses lane-contiguous b128.
#define XCH_OFF 36864

// ---------------- weight pre-pack: Wc[row][k] bf16, row = gate*512+j, k over [x|h] ----------
__global__ void convert_weights(const float* __restrict__ Wih,
                                const float* __restrict__ Whh,
                                __bf16* __restrict__ Wc) {
    int idx = blockIdx.x * 256 + threadIdx.x;
    if (idx >= G4n * Kn) return;
    int row = idx / Kn;
    int k   = idx - row * Kn;
    float v = (k < INn) ? Wih[row * INn + k] : Whh[row * Hn + (k - INn)];
    Wc[idx] = (__bf16)v;
}

// fast sigmoid: v_exp + single v_rcp (error ~1ulp << bf16 h-quantization)
__device__ __forceinline__ float sigf(float x)   { return __builtin_amdgcn_rcpf(1.0f + __expf(-x)); }
__device__ __forceinline__ float tanhf_f(float x){ return 2.0f * sigf(2.0f * x) - 1.0f; }

// ---------------- persistent LSTM scan ----------------
// 256 blocks x 512 threads (8 waves), 1 block/CU. Block = (rg_i: 32 batch rows) x (cb: 64 h-cols).
// Wave role: kh = wave&1 (K-half 288), wq = wave>>1 (16 h-cols). Each wave holds ALL 4
// GATES for its 16 cols (wreg[kb][gate], 144 regs) -> i/f/g/o for a cell are IN-LANE after
// the kh partial exchange: no z matrix in LDS. Exchange = raw MFMA fragments (identical
// layout in kh partners): 4 ds_write_b128 + 4 ds_read_b128, lane-contiguous.
// RULE-#20 FIX vs round-5: accumulators are NAMED acc0/acc1 (static register indices
// everywhere); the rg-role selection is done with wave-uniform if/else branches whose
// bodies use only compile-time indices, and with cndmask-style f32x4 selects. Runtime
// values appear ONLY in LDS/global ADDRESS arithmetic (legal), never as register-array
// subscripts. Round-5's acc[org] runtime subscript cost 3x (VALUBusy 55%).
// COHERENCE (proven scheme): all cross-block data via RELAXED agent-scope atomics
// (write-through/bypass to IC); __syncthreads drains vmcnt(0) before the barrier bump.
__global__ __launch_bounds__(512, 1) void lstm_persist(
    const float* __restrict__ xd,     // [B,T,IN]
    const float* __restrict__ bias,   // [4H]
    const __bf16* __restrict__ Wc,    // [4H][Kn]
    __bf16* __restrict__ h0,          // [B,H] buffer A (final h lands here)
    __bf16* __restrict__ h1,          // [B,H] buffer B
    unsigned int* __restrict__ bar)   // 32 groups x 32 uints (128B stride)
{
    __shared__ __align__(16) char smem[XCH_OFF + 32768];
    bf16x8* aTile = (bf16x8*)smem;
    f32x4*  xch   = (f32x4*)(smem + XCH_OFF);

    const int blk  = blockIdx.x;
    // group (rg_i) pinned to one XCD-slot (blk&7); 8 col-blocks per group
    const int rg_i = (blk & 7) * 4 + ((blk >> 3) & 3);   // 0..31 row-group
    const int cb   = blk >> 5;                           // 0..7  col-block
    const int m0   = rg_i << 5;
    const int j0   = cb << 6;

    const int tid  = threadIdx.x;              // 0..511
    const int wave = tid >> 6;                 // 0..7
    const int lane = tid & 63;
    const int q    = lane >> 4;
    const int l16  = lane & 15;

    const int kh   = wave & 1;                 // K half: kb 9*kh .. 9*kh+8
    const int wq   = wave >> 1;                // 16-col group (all 4 gates)
    const int myrg = kh;                       // row-group this wave finalizes
    const int org  = 1 - kh;                   // row-group it exports

    // ---- resident weights: 9 kb x 4 gates for cols j0 + wq*16 + l16 (144 regs) ----
    bf16x8 wreg[9][4];
    float  bini[4];
    const int wcol = j0 + wq * 16 + l16;
    #pragma unroll
    for (int cg = 0; cg < 4; ++cg) {
        #pragma unroll
        for (int kb = 0; kb < 9; ++kb)
            wreg[kb][cg] = *(const bf16x8*)(Wc + (size_t)(cg * Hn + wcol) * Kn
                                               + (kh * 9 + kb) * 32 + q * 8);
        bini[cg] = bias[cg * Hn + wcol];       // added once, into the finalized rg's init
    }

    // ---- c-state: 4 cells/lane (rows m0 + myrg*16 + q*4 + e, col wcol) ----
    float creg[4] = {0.f, 0.f, 0.f, 0.f};

    // ---- x staging: kh==0 waves, frag (xrg = wq>>1, xkb = wq&1) ----
    const bool  xown = (kh == 0);
    const float* xrb = xd + (size_t)(m0 + (wq >> 1) * 16 + l16) * (Tn * INn)
                          + (wq & 1) * 32 + q * 8;
    const int   xslot = ((wq >> 1) * 18 + (wq & 1)) * 64 + lane;

    unsigned int* cnt = bar + (rg_i << 5);     // one 128B line per group
    bool dead = false;

    // ---- prologue: stage x(t=0) ----
    if (xown) {
        f32x4 lo = *(const f32x4*)xrb;
        f32x4 hi = *(const f32x4*)(xrb + 4);
        bf16x8 v;
        v[0] = (__bf16)lo[0]; v[1] = (__bf16)lo[1]; v[2] = (__bf16)lo[2]; v[3] = (__bf16)lo[3];
        v[4] = (__bf16)hi[0]; v[5] = (__bf16)hi[1]; v[6] = (__bf16)hi[2]; v[7] = (__bf16)hi[3];
        aTile[xslot] = v;
    }

    for (int t = 0; t < Tn; ++t) {
        const __bf16* hread  = (t & 1) ? h1 : h0;
        __bf16*       hwrite = (t & 1) ? h0 : h1;

        // ---- phase 1: h -> regs (8 u64 loads all in flight), then -> LDS ----
        unsigned long long hu[4][2];
        #pragma unroll
        for (int i = 0; i < 4; ++i) {
            const int hf  = wave * 4 + i;
            const int rg  = hf >> 4;
            const int kbh = hf & 15;
            const unsigned long long* hp = (const unsigned long long*)
                (hread + (size_t)(m0 + rg * 16 + l16) * Hn + kbh * 32 + q * 8);
            hu[i][0] = __hip_atomic_load(hp,     __ATOMIC_RELAXED, __HIP_MEMORY_SCOPE_AGENT);
            hu[i][1] = __hip_atomic_load(hp + 1, __ATOMIC_RELAXED, __HIP_MEMORY_SCOPE_AGENT);
        }
        #pragma unroll
        for (int i = 0; i < 4; ++i) {
            const int hf  = wave * 4 + i;
            const int rg  = hf >> 4;
            const int kbh = hf & 15;
            union { unsigned long long u[2]; bf16x8 v; } cv;
            cv.u[0] = hu[i][0]; cv.u[1] = hu[i][1];
            aTile[(rg * 18 + kbh + 2) * 64 + lane] = cv.v;
        }
        __syncthreads();

        // ---- phase 2: MFMA (named acc0/acc1, all register indices STATIC) ----
        f32x4 acc0[4], acc1[4];
        #pragma unroll
        for (int cg = 0; cg < 4; ++cg) {
            const float b0 = (myrg == 0) ? bini[cg] : 0.f;   // scalar cndmask, cheap
            const float b1 = (myrg == 1) ? bini[cg] : 0.f;
            acc0[cg] = (f32x4){b0, b0, b0, b0};
            acc1[cg] = (f32x4){b1, b1, b1, b1};
        }
        #pragma unroll
        for (int kb = 0; kb < 9; ++kb) {
            const bf16x8 af0 = aTile[(0 * 18 + kh * 9 + kb) * 64 + lane];  // kh in ADDRESS: ok
            const bf16x8 af1 = aTile[(1 * 18 + kh * 9 + kb) * 64 + lane];
            #pragma unroll
            for (int cg = 0; cg < 4; ++cg) {
                acc0[cg] = __builtin_amdgcn_mfma_f32_16x16x32_bf16(af0, wreg[kb][cg], acc0[cg], 0, 0, 0);
                acc1[cg] = __builtin_amdgcn_mfma_f32_16x16x32_bf16(af1, wreg[kb][cg], acc1[cg], 0, 0, 0);
            }
        }
        // export the row-group the kh-partner finalizes: wave-uniform branch,
        // STATIC register indices inside each arm (LDS slot uses org implicitly)
        if (kh == 0) {
            #pragma unroll
            for (int cg = 0; cg < 4; ++cg)
                xch[((wq * 2 + 1) * 4 + cg) * 64 + lane] = acc1[cg];
        } else {
            #pragma unroll
            for (int cg = 0; cg < 4; ++cg)
                xch[((wq * 2 + 0) * 4 + cg) * 64 + lane] = acc0[cg];
        }
        __syncthreads();

        // ---- phase 3: partner sum + in-lane gates; x(t+1) under the latency ----
        f32x4 xlo, xhi;
        const bool mx = xown && (t + 1 < Tn);
        if (mx) {
            const float* xp = xrb + (size_t)(t + 1) * INn;
            xlo = *(const f32x4*)xp;
            xhi = *(const f32x4*)(xp + 4);
        }
        // own fragment: select with static indices (vector cndmask, 16 ops)
        f32x4 own[4];
        if (kh == 0) {
            #pragma unroll
            for (int cg = 0; cg < 4; ++cg) own[cg] = acc0[cg];
        } else {
            #pragma unroll
            for (int cg = 0; cg < 4; ++cg) own[cg] = acc1[cg];
        }
        float zs[4][4];
        #pragma unroll
        for (int cg = 0; cg < 4; ++cg) {
            const f32x4 p = xch[((wq * 2 + myrg) * 4 + cg) * 64 + lane];   // myrg in ADDRESS: ok
            #pragma unroll
            for (int e = 0; e < 4; ++e) zs[cg][e] = own[cg][e] + p[e];
        }
        __bf16* hcb = hwrite + (size_t)(m0 + myrg * 16 + q * 4) * Hn + wcol;
        #pragma unroll
        for (int e = 0; e < 4; ++e) {
            const float cn = sigf(zs[1][e]) * creg[e]
                           + sigf(zs[0][e]) * tanhf_f(zs[2][e]);
            creg[e] = cn;
            union { __bf16 b; unsigned short u; } hv;
            hv.b = (__bf16)(sigf(zs[3][e]) * tanhf_f(cn));
            __hip_atomic_store((unsigned short*)(hcb + (size_t)e * Hn),
                               hv.u, __ATOMIC_RELAXED, __HIP_MEMORY_SCOPE_AGENT);
        }

        // finish x(t+1) staging (loads have had the gate math to land)
        if (mx) {
            bf16x8 v;
            v[0] = (__bf16)xlo[0]; v[1] = (__bf16)xlo[1]; v[2] = (__bf16)xlo[2]; v[3] = (__bf16)xlo[3];
            v[4] = (__bf16)xhi[0]; v[5] = (__bf16)xhi[1]; v[6] = (__bf16)xhi[2]; v[7] = (__bf16)xhi[3];
            aTile[xslot] = v;
        }

        // ---- phase 4: group barrier (8 blocks sharing rg_i), relaxed atomics only ----
        __syncthreads();   // drains vmcnt(0): all write-through h stores at IC
        if (tid == 0) {
            __hip_atomic_fetch_add(cnt, 1u, __ATOMIC_RELAXED, __HIP_MEMORY_SCOPE_AGENT);
            if (!dead) {
                const unsigned int target = 8u * (unsigned int)(t + 1);
                int spins = 0;
                while (__hip_atomic_load(cnt, __ATOMIC_RELAXED, __HIP_MEMORY_SCOPE_AGENT) < target) {
                    __builtin_amdgcn_s_sleep(2);
                    if (++spins > 300000) { dead = true; break; }  // hang -> fast wrong-answer
                }
            }
        }
        __syncthreads();
    }
}

// ---------------- head: out[b] = relu(dot(h_T[b], Wl) + bl) ----------------
__global__ void head_kernel(const __bf16* __restrict__ h, const float* __restrict__ Wl,
                            const float* __restrict__ bl, float* __restrict__ out) {
    const int b = blockIdx.x;
    const int lane = threadIdx.x;  // 64 threads
    const __bf16* hp = h + (size_t)b * Hn;
    float s = 0.f;
    #pragma unroll
    for (int j = lane; j < Hn; j += 64) s += (float)hp[j] * Wl[j];
    #pragma unroll
    for (int off = 32; off > 0; off >>= 1) s += __shfl_down(s, off, 64);
    if (lane == 0) out[b] = fmaxf(s + bl[0], 0.0f);
}

extern "C" void kernel_launch(void* const* d_in, const int* in_sizes, int n_in,
                              void* d_out, int out_size, void* d_ws, size_t ws_size,
                              hipStream_t stream) {
    const float* xd  = (const float*)d_in[0];
    const float* Wih = (const float*)d_in[1];
    const float* Whh = (const float*)d_in[2];
    const float* b   = (const float*)d_in[3];
    const float* Wl  = (const float*)d_in[4];
    const float* bl  = (const float*)d_in[5];
    float* out = (float*)d_out;

    // ws layout:
    //   Wc  bf16 [2048][576] : 2,359,296 B
    //   h0  bf16 [1024][512] : 1,048,576 B
    //   h1  bf16 [1024][512] : 1,048,576 B
    //   bar u32  [32][32]    : 4,096 B
    char* ws = (char*)d_ws;
    __bf16* Wc = (__bf16*)ws;
    __bf16* h0 = (__bf16*)(ws + 2359296);
    __bf16* h1 = (__bf16*)(ws + 2359296 + 1048576);
    unsigned int* bar = (unsigned int*)(ws + 2359296 + 2 * 1048576);

    hipMemsetAsync(h0, 0, 1048576, stream);   // t=0 reads h0 as zeros
    hipMemsetAsync(bar, 0, 4096, stream);     // monotonic barrier counters (32 groups)

    const int total = G4n * Kn;
    convert_weights<<<(total + 255) / 256, 256, 0, stream>>>(Wih, Whh, Wc);

    lstm_persist<<<256, 512, 0, stream>>>(xd, b, Wc, h0, h1, bar);

    // t=729 (odd) writes h0 -> final hidden state is in h0
    head_kernel<<<Bn, 64, 0, stream>>>(h0, Wl, bl, out);
}

// Round 7
// 4157.077 us; speedup vs baseline: 2.4387x; 1.0665x over previous
//
#include <hip/hip_runtime.h>
#include <hip/hip_bf16.h>

#define Bn   1024
#define Tn   730
#define INn  64
#define Hn   512
#define Kn   576      // INn + Hn
#define G4n  2048     // 4*Hn

typedef __bf16 bf16x8 __attribute__((ext_vector_type(8)));
typedef float  f32x4  __attribute__((ext_vector_type(4)));

// LDS: A-tile 32x576 bf16 (fragment order) = 36864 B, then kh-exchange region:
// 4 wq x 2 rg x 4 gates x 64 lanes x 16B = 32768 B. All accesses lane-contiguous b128.
#define XCH_OFF 36864

// ---------------- weight pre-pack: Wc[row][k] bf16, row = gate*512+j, k over [x|h] ----------
__global__ void convert_weights(const float* __restrict__ Wih,
                                const float* __restrict__ Whh,
                                __bf16* __restrict__ Wc) {
    int idx = blockIdx.x * 256 + threadIdx.x;
    if (idx >= G4n * Kn) return;
    int row = idx / Kn;
    int k   = idx - row * Kn;
    float v = (k < INn) ? Wih[row * INn + k] : Whh[row * Hn + (k - INn)];
    Wc[idx] = (__bf16)v;
}

// fast sigmoid: v_exp + single v_rcp (error ~1ulp << bf16 h-quantization)
__device__ __forceinline__ float sigf(float x)   { return __builtin_amdgcn_rcpf(1.0f + __expf(-x)); }
__device__ __forceinline__ float tanhf_f(float x){ return 2.0f * sigf(2.0f * x) - 1.0f; }

// ---------------- persistent LSTM scan ----------------
// 256 blocks x 512 threads (8 waves), 1 block/CU. Block = (rg_i: 32 batch rows) x (cb: 64 h-cols).
// Wave role: kh = wave&1 (K-half 288), wq = wave>>1 (16 h-cols, ALL 4 gates: wreg[kb][gate]).
// OPERAND-SWAPPED MFMA (round-7): D = mfma(W_frag, A_frag) -> C layout transposed:
//   col(lane&15) = BATCH ROW, row(q*4+reg) = GATE-COL. Lane owns (1 batch row l16,
//   4 consecutive h-cols q*4+e) for all 4 gates -> i/f/g/o in-lane AND the h store is a
//   single coalesced u64 agent atomic (round-4's proven path; round-6's 4x2B scattered
//   stores cost +1.1us/step of drain stall).
// kh partial sums exchanged as raw MFMA fragments (identical layout in kh partners):
// 4 ds_write_b128 + 4 ds_read_b128, lane-contiguous, zero conflicts (measured r6).
// Rule-#20 discipline: acc0/acc1 NAMED, all register indices static; runtime wave role
// appears only in LDS/global ADDRESS arithmetic.
// COHERENCE (proven scheme): all cross-block data via RELAXED agent-scope atomics
// (write-through/bypass to IC); __syncthreads drains vmcnt(0) before the barrier bump.
__global__ __launch_bounds__(512, 1) void lstm_persist(
    const float* __restrict__ xd,     // [B,T,IN]
    const float* __restrict__ bias,   // [4H]
    const __bf16* __restrict__ Wc,    // [4H][Kn]
    __bf16* __restrict__ h0,          // [B,H] buffer A (final h lands here)
    __bf16* __restrict__ h1,          // [B,H] buffer B
    unsigned int* __restrict__ bar)   // 32 groups x 32 uints (128B stride)
{
    __shared__ __align__(16) char smem[XCH_OFF + 32768];
    bf16x8* aTile = (bf16x8*)smem;
    f32x4*  xch   = (f32x4*)(smem + XCH_OFF);

    const int blk  = blockIdx.x;
    // group (rg_i) pinned to one XCD-slot (blk&7); 8 col-blocks per group
    const int rg_i = (blk & 7) * 4 + ((blk >> 3) & 3);   // 0..31 row-group
    const int cb   = blk >> 5;                           // 0..7  col-block
    const int m0   = rg_i << 5;
    const int j0   = cb << 6;

    const int tid  = threadIdx.x;              // 0..511
    const int wave = tid >> 6;                 // 0..7
    const int lane = tid & 63;
    const int q    = lane >> 4;
    const int l16  = lane & 15;

    const int kh   = wave & 1;                 // K half: kb 9*kh .. 9*kh+8
    const int wq   = wave >> 1;                // 16-col group (all 4 gates)
    const int myrg = kh;                       // row-group this wave finalizes

    // ---- resident weights: 9 kb x 4 gates for cols j0 + wq*16 + l16 (144 regs) ----
    // (A-operand fragment: index l16 = gate-col within group, k = q*8..q*8+7)
    bf16x8 wreg[9][4];
    f32x4  bq[4];
    const int wcol = j0 + wq * 16 + l16;
    #pragma unroll
    for (int cg = 0; cg < 4; ++cg) {
        #pragma unroll
        for (int kb = 0; kb < 9; ++kb)
            wreg[kb][cg] = *(const bf16x8*)(Wc + (size_t)(cg * Hn + wcol) * Kn
                                               + (kh * 9 + kb) * 32 + q * 8);
        // bias for the 4 gate-cols this lane's acc elements represent: q*4+e
        bq[cg] = *(const f32x4*)(bias + cg * Hn + j0 + wq * 16 + q * 4);
    }

    // ---- c-state: 4 cells/lane: (row m0 + myrg*16 + l16, cols j0 + wq*16 + q*4 + e) ----
    float creg[4] = {0.f, 0.f, 0.f, 0.f};

    // ---- x staging: kh==0 waves, frag (xrg = wq>>1, xkb = wq&1) ----
    const bool  xown = (kh == 0);
    const float* xrb = xd + (size_t)(m0 + (wq >> 1) * 16 + l16) * (Tn * INn)
                          + (wq & 1) * 32 + q * 8;
    const int   xslot = ((wq >> 1) * 18 + (wq & 1)) * 64 + lane;

    unsigned int* cnt = bar + (rg_i << 5);     // one 128B line per group
    bool dead = false;

    // ---- prologue: stage x(t=0) ----
    if (xown) {
        f32x4 lo = *(const f32x4*)xrb;
        f32x4 hi = *(const f32x4*)(xrb + 4);
        bf16x8 v;
        v[0] = (__bf16)lo[0]; v[1] = (__bf16)lo[1]; v[2] = (__bf16)lo[2]; v[3] = (__bf16)lo[3];
        v[4] = (__bf16)hi[0]; v[5] = (__bf16)hi[1]; v[6] = (__bf16)hi[2]; v[7] = (__bf16)hi[3];
        aTile[xslot] = v;
    }

    for (int t = 0; t < Tn; ++t) {
        const __bf16* hread  = (t & 1) ? h1 : h0;
        __bf16*       hwrite = (t & 1) ? h0 : h1;

        // ---- phase 1: h -> regs (8 u64 loads all in flight), then -> LDS ----
        unsigned long long hu[4][2];
        #pragma unroll
        for (int i = 0; i < 4; ++i) {
            const int hf  = wave * 4 + i;
            const int rg  = hf >> 4;
            const int kbh = hf & 15;
            const unsigned long long* hp = (const unsigned long long*)
                (hread + (size_t)(m0 + rg * 16 + l16) * Hn + kbh * 32 + q * 8);
            hu[i][0] = __hip_atomic_load(hp,     __ATOMIC_RELAXED, __HIP_MEMORY_SCOPE_AGENT);
            hu[i][1] = __hip_atomic_load(hp + 1, __ATOMIC_RELAXED, __HIP_MEMORY_SCOPE_AGENT);
        }
        #pragma unroll
        for (int i = 0; i < 4; ++i) {
            const int hf  = wave * 4 + i;
            const int rg  = hf >> 4;
            const int kbh = hf & 15;
            union { unsigned long long u[2]; bf16x8 v; } cv;
            cv.u[0] = hu[i][0]; cv.u[1] = hu[i][1];
            aTile[(rg * 18 + kbh + 2) * 64 + lane] = cv.v;
        }
        __syncthreads();

        // ---- phase 2: MFMA, OPERANDS SWAPPED (W as A, activations as B) ----
        f32x4 acc0[4], acc1[4];
        const f32x4 zero = {0.f, 0.f, 0.f, 0.f};
        #pragma unroll
        for (int cg = 0; cg < 4; ++cg) {
            acc0[cg] = (kh == 0) ? bq[cg] : zero;   // bias once, in the finalizer wave
            acc1[cg] = (kh == 1) ? bq[cg] : zero;
        }
        #pragma unroll
        for (int kb = 0; kb < 9; ++kb) {
            const bf16x8 af0 = aTile[(0 * 18 + kh * 9 + kb) * 64 + lane];  // kh in ADDRESS: ok
            const bf16x8 af1 = aTile[(1 * 18 + kh * 9 + kb) * 64 + lane];
            #pragma unroll
            for (int cg = 0; cg < 4; ++cg) {
                acc0[cg] = __builtin_amdgcn_mfma_f32_16x16x32_bf16(wreg[kb][cg], af0, acc0[cg], 0, 0, 0);
                acc1[cg] = __builtin_amdgcn_mfma_f32_16x16x32_bf16(wreg[kb][cg], af1, acc1[cg], 0, 0, 0);
            }
        }
        // export the row-group the kh-partner finalizes: wave-uniform branch,
        // STATIC register indices inside each arm
        if (kh == 0) {
            #pragma unroll
            for (int cg = 0; cg < 4; ++cg)
                xch[((wq * 2 + 1) * 4 + cg) * 64 + lane] = acc1[cg];
        } else {
            #pragma unroll
            for (int cg = 0; cg < 4; ++cg)
                xch[((wq * 2 + 0) * 4 + cg) * 64 + lane] = acc0[cg];
        }
        __syncthreads();

        // ---- phase 3: partner sum + in-lane gates; x(t+1) under the latency ----
        f32x4 xlo, xhi;
        const bool mx = xown && (t + 1 < Tn);
        if (mx) {
            const float* xp = xrb + (size_t)(t + 1) * INn;
            xlo = *(const f32x4*)xp;
            xhi = *(const f32x4*)(xp + 4);
        }
        // zs[gate] = own partial + partner partial (static register indices both arms)
        f32x4 zs[4];
        if (kh == 0) {
            #pragma unroll
            for (int cg = 0; cg < 4; ++cg)
                zs[cg] = acc0[cg] + xch[((wq * 2 + 0) * 4 + cg) * 64 + lane];
        } else {
            #pragma unroll
            for (int cg = 0; cg < 4; ++cg)
                zs[cg] = acc1[cg] + xch[((wq * 2 + 1) * 4 + cg) * 64 + lane];
        }
        // cells: (row l16, col q*4+e) — all 4 gates in-lane, store 1 coalesced u64
        union { unsigned long long u; __bf16 h[4]; } pk;
        #pragma unroll
        for (int e = 0; e < 4; ++e) {
            const float cn = sigf(zs[1][e]) * creg[e]
                           + sigf(zs[0][e]) * tanhf_f(zs[2][e]);
            creg[e] = cn;
            pk.h[e] = (__bf16)(sigf(zs[3][e]) * tanhf_f(cn));
        }
        __hip_atomic_store((unsigned long long*)
                           (hwrite + (size_t)(m0 + myrg * 16 + l16) * Hn + j0 + wq * 16 + q * 4),
                           pk.u, __ATOMIC_RELAXED, __HIP_MEMORY_SCOPE_AGENT);

        // finish x(t+1) staging (loads have had the gate math to land)
        if (mx) {
            bf16x8 v;
            v[0] = (__bf16)xlo[0]; v[1] = (__bf16)xlo[1]; v[2] = (__bf16)xlo[2]; v[3] = (__bf16)xlo[3];
            v[4] = (__bf16)xhi[0]; v[5] = (__bf16)xhi[1]; v[6] = (__bf16)xhi[2]; v[7] = (__bf16)xhi[3];
            aTile[xslot] = v;
        }

        // ---- phase 4: group barrier (8 blocks sharing rg_i), relaxed atomics only ----
        __syncthreads();   // drains vmcnt(0): all write-through h stores at IC
        if (tid == 0) {
            __hip_atomic_fetch_add(cnt, 1u, __ATOMIC_RELAXED, __HIP_MEMORY_SCOPE_AGENT);
            if (!dead) {
                const unsigned int target = 8u * (unsigned int)(t + 1);
                int spins = 0;
                while (__hip_atomic_load(cnt, __ATOMIC_RELAXED, __HIP_MEMORY_SCOPE_AGENT) < target) {
                    __builtin_amdgcn_s_sleep(2);
                    if (++spins > 300000) { dead = true; break; }  // hang -> fast wrong-answer
                }
            }
        }
        __syncthreads();
    }
}

// ---------------- head: out[b] = relu(dot(h_T[b], Wl) + bl) ----------------
__global__ void head_kernel(const __bf16* __restrict__ h, const float* __restrict__ Wl,
                            const float* __restrict__ bl, float* __restrict__ out) {
    const int b = blockIdx.x;
    const int lane = threadIdx.x;  // 64 threads
    const __bf16* hp = h + (size_t)b * Hn;
    float s = 0.f;
    #pragma unroll
    for (int j = lane; j < Hn; j += 64) s += (float)hp[j] * Wl[j];
    #pragma unroll
    for (int off = 32; off > 0; off >>= 1) s += __shfl_down(s, off, 64);
    if (lane == 0) out[b] = fmaxf(s + bl[0], 0.0f);
}

extern "C" void kernel_launch(void* const* d_in, const int* in_sizes, int n_in,
                              void* d_out, int out_size, void* d_ws, size_t ws_size,
                              hipStream_t stream) {
    const float* xd  = (const float*)d_in[0];
    const float* Wih = (const float*)d_in[1];
    const float* Whh = (const float*)d_in[2];
    const float* b   = (const float*)d_in[3];
    const float* Wl  = (const float*)d_in[4];
    const float* bl  = (const float*)d_in[5];
    float* out = (float*)d_out;

    // ws layout:
    //   Wc  bf16 [2048][576] : 2,359,296 B
    //   h0  bf16 [1024][512] : 1,048,576 B
    //   h1  bf16 [1024][512] : 1,048,576 B
    //   bar u32  [32][32]    : 4,096 B
    char* ws = (char*)d_ws;
    __bf16* Wc = (__bf16*)ws;
    __bf16* h0 = (__bf16*)(ws + 2359296);
    __bf16* h1 = (__bf16*)(ws + 2359296 + 1048576);
    unsigned int* bar = (unsigned int*)(ws + 2359296 + 2 * 1048576);

    hipMemsetAsync(h0, 0, 1048576, stream);   // t=0 reads h0 as zeros
    hipMemsetAsync(bar, 0, 4096, stream);     // monotonic barrier counters (32 groups)

    const int total = G4n * Kn;
    convert_weights<<<(total + 255) / 256, 256, 0, stream>>>(Wih, Whh, Wc);

    lstm_persist<<<256, 512, 0, stream>>>(xd, b, Wc, h0, h1, bar);

    // t=729 (odd) writes h0 -> final hidden state is in h0
    head_kernel<<<Bn, 64, 0, stream>>>(h0, Wl, bl, out);
}

// Round 8
// 3959.021 us; speedup vs baseline: 2.5607x; 1.0500x over previous
//
#include <hip/hip_runtime.h>
#include <hip/hip_bf16.h>

#define Bn   1024
#define Tn   730
#define INn  64
#define Hn   512
#define Kn   576      // INn + Hn
#define G4n  2048     // 4*Hn

typedef __bf16 bf16x8 __attribute__((ext_vector_type(8)));
typedef float  f32x4  __attribute__((ext_vector_type(4)));

// Block tile: 32 batch rows x 64 h-cols (256 gate-cols), K full 576.
// A-tile: 32 x 576 bf16 in MFMA-fragment order = 36864 B.
// z exchange: [32 rows][2 khalf][256 gatecols], row stride ZROW=524 floats
// (524 mod 32 = 12 -> scatter 2-way-free (m136), f32x4 gather uniform; measured
// 4.8e7 conflicts in round-4 = ~260 cy/CU/step, negligible).
#define ZROW   524
#define Z_OFF  36864

// ---------------- weight pre-pack: Wc[row][k] bf16, row = gate*512+j, k over [x|h] ----------
__global__ void convert_weights(const float* __restrict__ Wih,
                                const float* __restrict__ Whh,
                                __bf16* __restrict__ Wc) {
    int idx = blockIdx.x * 256 + threadIdx.x;
    if (idx >= G4n * Kn) return;
    int row = idx / Kn;
    int k   = idx - row * Kn;
    float v = (k < INn) ? Wih[row * INn + k] : Whh[row * Hn + (k - INn)];
    Wc[idx] = (__bf16)v;
}

// fast sigmoid: v_exp + single v_rcp (error ~1ulp << bf16 h-quantization)
__device__ __forceinline__ float sigf(float x)   { return __builtin_amdgcn_rcpf(1.0f + __expf(-x)); }
__device__ __forceinline__ float tanhf_f(float x){ return 2.0f * sigf(2.0f * x) - 1.0f; }

// ---------------- persistent LSTM scan ----------------
// ROUND-4 TRUNK (3631us) with ONE change: the group barrier's central fetch_add counter
// is replaced by PER-PRODUCER FLAGS + PER-WAVE POLLING.
//   old: drain-sync -> 8 contending RMWs on one line -> tid0 spin -> release-sync
//   new: drain-sync -> tid0 plain agent store flag[rg_i][cb]=t+1 (own 128B line)
//        next iter: each WAVE polls only the 2 producers whose cols it stages
//        (kbh>>1 is wave-uniform -> broadcast load), release-sync DELETED.
// Safety: collectively the 8 waves poll all 8 producers before the phase1->2
// __syncthreads, so the block cannot reach its next h-store until every peer finished
// the prior step -> no buffer overwrite race. LDS writes before that sync are
// wave-disjoint (own h-slots / own x-slot). Flag visibility: h stores are vmcnt-drained
// (acked at IC) before the flag store issues — same ordering guarantee the counter used.
// COHERENCE: all cross-block data via RELAXED agent-scope atomics (write-through/bypass
// to IC), proven rounds 0-7.
__global__ __launch_bounds__(512, 1) void lstm_persist(
    const float* __restrict__ xd,     // [B,T,IN]
    const float* __restrict__ bias,   // [4H]
    const __bf16* __restrict__ Wc,    // [4H][Kn]
    __bf16* __restrict__ h0,          // [B,H] buffer A (final h lands here)
    __bf16* __restrict__ h1,          // [B,H] buffer B
    unsigned int* __restrict__ bar)   // flags: [32 groups][8 producers] x 32 uints (128B stride)
{
    // LDS: A-tile 36864 B + z 32*524*4 = 67072 B -> 103936 B (1 block/CU)
    __shared__ __align__(16) char smem[Z_OFF + ZROW * 32 * 4];
    bf16x8* aTile = (bf16x8*)smem;
    float*  zT    = (float*)(smem + Z_OFF);

    const int blk  = blockIdx.x;
    // group (rg_i) pinned to one XCD-slot (blk&7); 8 col-blocks per group
    const int rg_i = (blk & 7) * 4 + ((blk >> 3) & 3);   // 0..31 row-group
    const int cb   = blk >> 5;                           // 0..7  col-block (= producer id)
    const int m0   = rg_i << 5;
    const int j0   = cb << 6;

    const int tid  = threadIdx.x;              // 0..511
    const int wave = tid >> 6;                 // 0..7
    const int lane = tid & 63;
    const int q    = lane >> 4;
    const int l16  = lane & 15;

    const int kh = wave & 1;                   // K half: kb 9*kh .. 9*kh+8
    const int cq = wave >> 1;                  // gate-col quarter (64 of 256)

    // ---- resident weights: 9 kb x 4 colgroups; gcg = cq*4+cg -> gate = gcg>>2, jsub = gcg&3 ----
    bf16x8 wreg[9][4];
    float  bini[4];
    #pragma unroll
    for (int cg = 0; cg < 4; ++cg) {
        const int gcg  = cq * 4 + cg;
        const int gate = gcg >> 2;
        const int col  = j0 + (gcg & 3) * 16 + l16;
        #pragma unroll
        for (int kb = 0; kb < 9; ++kb)
            wreg[kb][cg] = *(const bf16x8*)(Wc + (size_t)(gate * Hn + col) * Kn
                                               + (kh * 9 + kb) * 32 + q * 8);
        bini[cg] = kh ? 0.f : bias[gate * Hn + col];   // bias folded into kh=0 acc init
    }

    // ---- pointwise ownership: thread -> (row r of 32, 4 consecutive cols) ----
    const int r  = tid >> 4;                   // 0..31
    const int c4 = (tid & 15) << 2;            // 0..60
    float creg[4] = {0.f, 0.f, 0.f, 0.f};

    // ---- h staging: wave stages frags hf = wave*4 + i (rg = hf>>4, kbh = hf&15) ----
    // producers polled by this wave: cols kbh*32 with kbh in [4*(wave&3), 4*(wave&3)+3]
    // -> producer ids 2*(wave&3), 2*(wave&3)+1 (wave-uniform).
    const int p0 = (wave & 3) * 2;
    unsigned int* flg0  = bar + ((rg_i * 8 + p0)     << 5);
    unsigned int* flg1  = bar + ((rg_i * 8 + p0 + 1) << 5);
    unsigned int* myflg = bar + ((rg_i * 8 + cb)     << 5);

    // ---- x staging: threads 0..255, frag f = tid>>6 (rg = f>>1, kb = f&1) ----
    const int xt    = tid & 255;
    const int xrg   = (xt >> 7) & 1;
    const int xkb   = (xt >> 6) & 1;
    const int xlane = xt & 63;
    const int xq    = xlane >> 4;
    const int xl16  = xlane & 15;
    const float* xrb = xd + (size_t)(m0 + xrg * 16 + xl16) * (Tn * INn) + xkb * 32 + xq * 8;
    const int xslot  = (xrg * 18 + xkb) * 64 + xlane;
    const bool xown  = (tid < 256);

    bool dead = false;

    // ---- prologue: stage x(t=0) ----
    if (xown) {
        f32x4 lo = *(const f32x4*)xrb;
        f32x4 hi = *(const f32x4*)(xrb + 4);
        bf16x8 v;
        v[0] = (__bf16)lo[0]; v[1] = (__bf16)lo[1]; v[2] = (__bf16)lo[2]; v[3] = (__bf16)lo[3];
        v[4] = (__bf16)hi[0]; v[5] = (__bf16)hi[1]; v[6] = (__bf16)hi[2]; v[7] = (__bf16)hi[3];
        aTile[xslot] = v;
    }

    for (int t = 0; t < Tn; ++t) {
        const __bf16* hread  = (t & 1) ? h1 : h0;
        __bf16*       hwrite = (t & 1) ? h0 : h1;

        // ---- phase 0: per-wave poll of this wave's 2 producers (wave-uniform) ----
        if (t > 0 && !dead) {
            const unsigned int tgt = (unsigned int)t;
            int spins = 0;
            while (__hip_atomic_load(flg0, __ATOMIC_RELAXED, __HIP_MEMORY_SCOPE_AGENT) < tgt ||
                   __hip_atomic_load(flg1, __ATOMIC_RELAXED, __HIP_MEMORY_SCOPE_AGENT) < tgt) {
                __builtin_amdgcn_s_sleep(1);
                if (++spins > 600000) { dead = true; break; }   // hang -> fast wrong-answer
            }
        }

        // ---- phase 1: h -> regs (4 u64 loads all in flight), then -> LDS ----
        unsigned long long hu[4][2];
        #pragma unroll
        for (int i = 0; i < 4; ++i) {
            const int hf  = wave * 4 + i;
            const int rg  = hf >> 4;
            const int kbh = hf & 15;
            const unsigned long long* hp = (const unsigned long long*)
                (hread + (size_t)(m0 + rg * 16 + l16) * Hn + kbh * 32 + q * 8);
            hu[i][0] = __hip_atomic_load(hp,     __ATOMIC_RELAXED, __HIP_MEMORY_SCOPE_AGENT);
            hu[i][1] = __hip_atomic_load(hp + 1, __ATOMIC_RELAXED, __HIP_MEMORY_SCOPE_AGENT);
        }
        #pragma unroll
        for (int i = 0; i < 4; ++i) {
            const int hf  = wave * 4 + i;
            const int rg  = hf >> 4;
            const int kbh = hf & 15;
            union { unsigned long long u[2]; bf16x8 v; } cv;
            cv.u[0] = hu[i][0]; cv.u[1] = hu[i][1];
            aTile[(rg * 18 + kbh + 2) * 64 + lane] = cv.v;
        }
        __syncthreads();   // aligns all waves; collectively all 8 producers were polled

        // ---- phase 2: MFMA: wave's (32 rows x 64 gatecols x K-half); A from LDS ----
        f32x4 acc[2][4];
        #pragma unroll
        for (int rg = 0; rg < 2; ++rg)
            #pragma unroll
            for (int cg = 0; cg < 4; ++cg)
                acc[rg][cg] = (f32x4){bini[cg], bini[cg], bini[cg], bini[cg]};
        #pragma unroll
        for (int kb = 0; kb < 9; ++kb) {
            const bf16x8 af0 = aTile[(0 * 18 + kh * 9 + kb) * 64 + lane];
            const bf16x8 af1 = aTile[(1 * 18 + kh * 9 + kb) * 64 + lane];
            #pragma unroll
            for (int cg = 0; cg < 4; ++cg) {
                acc[0][cg] = __builtin_amdgcn_mfma_f32_16x16x32_bf16(af0, wreg[kb][cg], acc[0][cg], 0, 0, 0);
                acc[1][cg] = __builtin_amdgcn_mfma_f32_16x16x32_bf16(af1, wreg[kb][cg], acc[1][cg], 0, 0, 0);
            }
        }
        // z scatter: row = rg*16 + q*4 + e; linear gatecol = (cq*4+cg)*16 + l16
        #pragma unroll
        for (int rg = 0; rg < 2; ++rg)
            #pragma unroll
            for (int cg = 0; cg < 4; ++cg)
                #pragma unroll
                for (int e = 0; e < 4; ++e)
                    zT[(rg * 16 + q * 4 + e) * ZROW + kh * 256 + (cq * 4 + cg) * 16 + l16]
                        = acc[rg][cg][e];
        __syncthreads();

        // ---- phase 3: issue x(t+1) loads; pointwise under their latency ----
        f32x4 xlo, xhi;
        const bool mx = xown && (t + 1 < Tn);
        if (mx) {
            const float* xp = xrb + (size_t)(t + 1) * INn;
            xlo = *(const f32x4*)xp;
            xhi = *(const f32x4*)(xp + 4);
        }

        // gate pointwise: f32x4 gather of both K-halves, sum, activate
        float zg[4][4];
        #pragma unroll
        for (int g = 0; g < 4; ++g) {
            f32x4 v0 = *(const f32x4*)&zT[r * ZROW +       g * 64 + c4];
            f32x4 v1 = *(const f32x4*)&zT[r * ZROW + 256 + g * 64 + c4];
            f32x4 s  = v0 + v1;
            zg[g][0] = s[0]; zg[g][1] = s[1]; zg[g][2] = s[2]; zg[g][3] = s[3];
        }
        union { unsigned long long u; __bf16 h[4]; } pk;
        #pragma unroll
        for (int cc = 0; cc < 4; ++cc) {
            const float cn = sigf(zg[1][cc]) * creg[cc]
                           + sigf(zg[0][cc]) * tanhf_f(zg[2][cc]);
            creg[cc] = cn;
            pk.h[cc] = (__bf16)(sigf(zg[3][cc]) * tanhf_f(cn));
        }
        __hip_atomic_store((unsigned long long*)(hwrite + (size_t)(m0 + r) * Hn + j0 + c4),
                           pk.u, __ATOMIC_RELAXED, __HIP_MEMORY_SCOPE_AGENT);

        // finish x(t+1) staging (loads have had the gate math to land)
        if (mx) {
            bf16x8 v;
            v[0] = (__bf16)xlo[0]; v[1] = (__bf16)xlo[1]; v[2] = (__bf16)xlo[2]; v[3] = (__bf16)xlo[3];
            v[4] = (__bf16)xhi[0]; v[5] = (__bf16)xhi[1]; v[6] = (__bf16)xhi[2]; v[7] = (__bf16)xhi[3];
            aTile[xslot] = v;
        }

        // ---- phase 4: drain + flag store (no RMW, no release-sync) ----
        __syncthreads();   // drains vmcnt(0): all write-through h stores acked at IC;
                           // also the LDS fence for next iter's phase-1 writes
        if (tid == 0)
            __hip_atomic_store(myflg, (unsigned int)(t + 1),
                               __ATOMIC_RELAXED, __HIP_MEMORY_SCOPE_AGENT);
    }
}

// ---------------- head: out[b] = relu(dot(h_T[b], Wl) + bl) ----------------
__global__ void head_kernel(const __bf16* __restrict__ h, const float* __restrict__ Wl,
                            const float* __restrict__ bl, float* __restrict__ out) {
    const int b = blockIdx.x;
    const int lane = threadIdx.x;  // 64 threads
    const __bf16* hp = h + (size_t)b * Hn;
    float s = 0.f;
    #pragma unroll
    for (int j = lane; j < Hn; j += 64) s += (float)hp[j] * Wl[j];
    #pragma unroll
    for (int off = 32; off > 0; off >>= 1) s += __shfl_down(s, off, 64);
    if (lane == 0) out[b] = fmaxf(s + bl[0], 0.0f);
}

extern "C" void kernel_launch(void* const* d_in, const int* in_sizes, int n_in,
                              void* d_out, int out_size, void* d_ws, size_t ws_size,
                              hipStream_t stream) {
    const float* xd  = (const float*)d_in[0];
    const float* Wih = (const float*)d_in[1];
    const float* Whh = (const float*)d_in[2];
    const float* b   = (const float*)d_in[3];
    const float* Wl  = (const float*)d_in[4];
    const float* bl  = (const float*)d_in[5];
    float* out = (float*)d_out;

    // ws layout:
    //   Wc    bf16 [2048][576]   : 2,359,296 B
    //   h0    bf16 [1024][512]   : 1,048,576 B
    //   h1    bf16 [1024][512]   : 1,048,576 B
    //   flags u32  [32][8][32]   : 32,768 B   (128B line per producer flag)
    char* ws = (char*)d_ws;
    __bf16* Wc = (__bf16*)ws;
    __bf16* h0 = (__bf16*)(ws + 2359296);
    __bf16* h1 = (__bf16*)(ws + 2359296 + 1048576);
    unsigned int* bar = (unsigned int*)(ws + 2359296 + 2 * 1048576);

    hipMemsetAsync(h0, 0, 1048576, stream);   // t=0 reads h0 as zeros
    hipMemsetAsync(bar, 0, 32768, stream);    // monotonic flags

    const int total = G4n * Kn;
    convert_weights<<<(total + 255) / 256, 256, 0, stream>>>(Wih, Whh, Wc);

    lstm_persist<<<256, 512, 0, stream>>>(xd, b, Wc, h0, h1, bar);

    // t=729 (odd) writes h0 -> final hidden state is in h0
    head_kernel<<<Bn, 64, 0, stream>>>(h0, Wl, bl, out);
}